// Round 1
// baseline (1263.661 us; speedup 1.0000x reference)
//
#include <hip/hip_runtime.h>

// Problem: B=2048, N=49 (7x7 grid), D=512, H=8, DK=DV=64.
// out = softmax((XWq^T)(XWk^T)^T * dilate_mask / 8) (XWv^T) @ Wo^T + bo
// dilate mask p=1: Chebyshev distance == 1 (8-neighborhood); multiplicative
// BEFORE softmax, so masked entries score 0 and contribute exp(0)=1.
//
// Kernel 1: QKV projection GEMM (3x M=100352,N=512,K=512), fp32 in -> bf16
//           staged LDS -> mfma 16x16x32 bf16 -> bf16 q/k/v in d_ws (308 MB).
// Kernel 2: per-batch fused attention + output projection (never writes the
//           per-head attention output to HBM).

#define MTOT 100352  // 2048*49

typedef float f32x4 __attribute__((ext_vector_type(4)));
typedef __bf16 bf16x8 __attribute__((ext_vector_type(8)));
typedef unsigned short us8v __attribute__((ext_vector_type(8)));

__device__ __forceinline__ unsigned short f2bf(float f) {
    unsigned int u = __float_as_uint(f);
    u += 0x7fffu + ((u >> 16) & 1u);   // round-to-nearest-even
    return (unsigned short)(u >> 16);
}

__device__ __forceinline__ bf16x8 ld_frag(const unsigned short* p) {
    us8v r = *(const us8v*)p;
    return __builtin_bit_cast(bf16x8, r);
}

__device__ __forceinline__ f32x4 mfma16(bf16x8 a, bf16x8 b, f32x4 c) {
    return __builtin_amdgcn_mfma_f32_16x16x32_bf16(a, b, c, 0, 0, 0);
}

// ---------------- Kernel 1: QKV projection GEMM --------------------------
// grid (4 ntiles, 784 mtiles, 3 sel), block 256. 128x128 tile, BK=64.
// A = X[sel] (M x 512 fp32), B^T = W[sel] (N=512 rows x K=512, K-major ->
// exactly the m97 "B^T" pattern). Inline fp32->bf16 conversion in staging.
__global__ __launch_bounds__(256) void proj_gemm(
    const float* __restrict__ Xq, const float* __restrict__ Xk, const float* __restrict__ Xv,
    const float* __restrict__ Wq, const float* __restrict__ Wk, const float* __restrict__ Wv,
    const float* __restrict__ bq, const float* __restrict__ bk, const float* __restrict__ bv,
    unsigned short* __restrict__ outbase)
{
    const int s = blockIdx.z;
    const float* X    = (s == 0) ? Xq : (s == 1) ? Xk : Xv;
    const float* W    = (s == 0) ? Wq : (s == 1) ? Wk : Wv;
    const float* bias = (s == 0) ? bq : (s == 1) ? bk : bv;
    unsigned short* out = outbase + (size_t)s * MTOT * 512;

    const int mbase = blockIdx.y * 128;
    const int nbase = blockIdx.x * 128;

    // stride 72 elements (144 B): 16B-aligned b128 reads, 2-way banks (free)
    __shared__ __align__(16) unsigned short smA[128 * 72];
    __shared__ __align__(16) unsigned short smB[128 * 72];

    const int tid  = threadIdx.x;
    const int wave = tid >> 6, lane = tid & 63;
    const int lm   = lane & 15, quad = lane >> 4;
    const int wm   = (wave & 1) * 64, wn = (wave >> 1) * 64;

    f32x4 acc[4][4];
#pragma unroll
    for (int i = 0; i < 4; i++)
#pragma unroll
        for (int j = 0; j < 4; j++) acc[i][j] = (f32x4){0.f, 0.f, 0.f, 0.f};

    for (int k0 = 0; k0 < 512; k0 += 64) {
        // stage 128x64 fp32 -> bf16 for A and B: 2048 float4 each, 8/thread
#pragma unroll
        for (int i = 0; i < 8; i++) {
            int f   = tid + 256 * i;       // 0..2047
            int row = f >> 4;              // 16 float4 per 64-wide row
            int c4  = (f & 15) * 4;
            float4 av = *(const float4*)(X + (size_t)(mbase + row) * 512 + k0 + c4);
            ushort4 wa;
            wa.x = f2bf(av.x); wa.y = f2bf(av.y); wa.z = f2bf(av.z); wa.w = f2bf(av.w);
            *(ushort4*)(smA + row * 72 + c4) = wa;
            float4 bv4 = *(const float4*)(W + (size_t)(nbase + row) * 512 + k0 + c4);
            ushort4 wb;
            wb.x = f2bf(bv4.x); wb.y = f2bf(bv4.y); wb.z = f2bf(bv4.z); wb.w = f2bf(bv4.w);
            *(ushort4*)(smB + row * 72 + c4) = wb;
        }
        __syncthreads();
#pragma unroll
        for (int kk = 0; kk < 64; kk += 32) {
            bf16x8 af[4], bfr[4];
#pragma unroll
            for (int mi = 0; mi < 4; mi++)
                af[mi] = ld_frag(smA + (wm + mi * 16 + lm) * 72 + kk + quad * 8);
#pragma unroll
            for (int ni = 0; ni < 4; ni++)
                bfr[ni] = ld_frag(smB + (wn + ni * 16 + lm) * 72 + kk + quad * 8);
#pragma unroll
            for (int mi = 0; mi < 4; mi++)
#pragma unroll
                for (int ni = 0; ni < 4; ni++)
                    acc[mi][ni] = mfma16(af[mi], bfr[ni], acc[mi][ni]);
        }
        __syncthreads();
    }

    // epilogue: C layout col=lane&15, row=quad*4+reg (verified m89/m91)
#pragma unroll
    for (int mi = 0; mi < 4; mi++) {
#pragma unroll
        for (int ni = 0; ni < 4; ni++) {
            int n = nbase + wn + ni * 16 + lm;
            float bb = bias[n];
#pragma unroll
            for (int r = 0; r < 4; r++) {
                int m = mbase + wm + mi * 16 + quad * 4 + r;
                out[(size_t)m * 512 + n] = f2bf(acc[mi][ni][r] + bb);
            }
        }
    }
}

// ---------------- Kernel 2: fused attention + output projection ----------
// one block per batch, 256 threads = 4 waves; heads sequential.
// LDS reuse: Pb aliases qb, Ob aliases kb (dead after S-mfma).
__global__ __launch_bounds__(256) void attn_fused(
    const unsigned short* __restrict__ qkv,
    const float* __restrict__ Wo, const float* __restrict__ bo,
    float* __restrict__ out)
{
    const int b   = blockIdx.x;
    const int tid = threadIdx.x;
    const int wave = tid >> 6, lane = tid & 63;
    const int lm = lane & 15, quad = lane >> 4;

    const size_t QK = (size_t)MTOT * 512;
    const unsigned short* qg = qkv;
    const unsigned short* kg = qkv + QK;
    const unsigned short* vg = qkv + 2 * QK;
    const size_t brow = (size_t)b * 49;

    __shared__ __align__(16) unsigned short qb[64 * 72];   // also P (bf16 A-layout)
    __shared__ __align__(16) unsigned short kb[64 * 72];   // also O (bf16 A-layout)
    __shared__ __align__(16) unsigned short vT[64 * 72];   // v transposed [d][key]
    __shared__ __align__(16) unsigned short Wos[64 * 72];  // Wo slice [n][k]
    __shared__ __align__(16) float Sb[64 * 68];            // scores fp32

    f32x4 oacc[4];
#pragma unroll
    for (int i = 0; i < 4; i++) oacc[i] = (f32x4){0.f, 0.f, 0.f, 0.f};

    for (int h = 0; h < 8; h++) {
        __syncthreads();  // protect previous iteration's LDS reads

        // ---- stage q, k (49 rows x 64 bf16, 8B vectors) ----
#pragma unroll
        for (int i = 0; i < 4; i++) {
            int f = tid + 256 * i;               // 784 ushort4 total
            if (f < 784) {
                int row = f >> 4, c = (f & 15) * 4;
                size_t src = (brow + row) * 512 + h * 64 + c;
                *(ushort4*)(qb + row * 72 + c) = *(const ushort4*)(qg + src);
                *(ushort4*)(kb + row * 72 + c) = *(const ushort4*)(kg + src);
            }
        }
        // ---- stage v transposed: vT[d][key] ----
#pragma unroll
        for (int i = 0; i < 13; i++) {
            int f = tid + 256 * i;
            if (f < 3136) {
                int row = f >> 6, d = f & 63;
                vT[d * 72 + row] = vg[(brow + row) * 512 + h * 64 + d];
            }
        }
        if (tid < 64) {                          // zero pad keys 49..63
#pragma unroll
            for (int c = 49; c < 64; c++) vT[tid * 72 + c] = 0;
        }
        // ---- stage Wo slice: Wos[n][k] = Wo[n][h*64+k], fp32 -> bf16 ----
#pragma unroll
        for (int i = 0; i < 4; i++) {
            int f = tid + 256 * i;               // 1024 float4
            int row = f >> 4, c = (f & 15) * 4;
            float4 wv = *(const float4*)(Wo + (size_t)row * 512 + h * 64 + c);
            ushort4 ww;
            ww.x = f2bf(wv.x); ww.y = f2bf(wv.y); ww.z = f2bf(wv.z); ww.w = f2bf(wv.w);
            *(ushort4*)(Wos + row * 72 + c) = ww;
        }
        __syncthreads();

        // ---- S = q @ k^T (M=64 pad, N=64 pad, K=64) ----
        f32x4 sacc[4];
#pragma unroll
        for (int i = 0; i < 4; i++) sacc[i] = (f32x4){0.f, 0.f, 0.f, 0.f};
#pragma unroll
        for (int kk = 0; kk < 64; kk += 32) {
            bf16x8 af = ld_frag(qb + (16 * wave + lm) * 72 + kk + quad * 8);
#pragma unroll
            for (int ni = 0; ni < 4; ni++) {
                bf16x8 bf = ld_frag(kb + (ni * 16 + lm) * 72 + kk + quad * 8);
                sacc[ni] = mfma16(af, bf, sacc[ni]);
            }
        }
#pragma unroll
        for (int ni = 0; ni < 4; ni++)
#pragma unroll
            for (int r = 0; r < 4; r++)
                Sb[(16 * wave + quad * 4 + r) * 68 + ni * 16 + lm] = sacc[ni][r];
        __syncthreads();

        // ---- mask (Chebyshev==1), scale 1/8, softmax over ALL 49 cols ----
        if (tid < 49) {
            int row = tid, ir = row / 7, ic = row % 7;
            float sum = 0.f;
            for (int j = 0; j < 49; j++) {
                int jr = j / 7, jc = j % 7;
                int dr = ir - jr; dr = dr < 0 ? -dr : dr;
                int dc = ic - jc; dc = dc < 0 ? -dc : dc;
                int ch = dr > dc ? dr : dc;
                float sv = (ch == 1) ? Sb[row * 68 + j] * 0.125f : 0.f;
                float e = __expf(sv);
                Sb[row * 68 + j] = e;
                sum += e;
            }
            float inv = 1.f / sum;
            for (int j = 0; j < 64; j++)    // P into qb (bf16), zero pad cols
                qb[row * 72 + j] = (j < 49) ? f2bf(Sb[row * 68 + j] * inv)
                                            : (unsigned short)0;
        } else if (tid < 64) {              // zero pad rows 49..63
            for (int j = 0; j < 64; j++) qb[tid * 72 + j] = 0;
        }
        __syncthreads();

        // ---- O = P @ v (K = keys, padded to 64 with zeros) ----
        f32x4 pacc[4];
#pragma unroll
        for (int i = 0; i < 4; i++) pacc[i] = (f32x4){0.f, 0.f, 0.f, 0.f};
#pragma unroll
        for (int kk = 0; kk < 64; kk += 32) {
            bf16x8 af = ld_frag(qb + (16 * wave + lm) * 72 + kk + quad * 8);
#pragma unroll
            for (int ni = 0; ni < 4; ni++) {
                bf16x8 bf = ld_frag(vT + (ni * 16 + lm) * 72 + kk + quad * 8);
                pacc[ni] = mfma16(af, bf, pacc[ni]);
            }
        }
        // O -> LDS (kb) in bf16 A-layout for the out-projection
#pragma unroll
        for (int ni = 0; ni < 4; ni++)
#pragma unroll
            for (int r = 0; r < 4; r++)
                kb[(16 * wave + quad * 4 + r) * 72 + ni * 16 + lm] = f2bf(pacc[ni][r]);
        __syncthreads();

        // ---- out += O_h @ Wo[:, h*64:(h+1)*64]^T, accumulate in regs ----
#pragma unroll
        for (int kk = 0; kk < 64; kk += 32) {
            bf16x8 af = ld_frag(kb + (16 * wave + lm) * 72 + kk + quad * 8);
#pragma unroll
            for (int ni = 0; ni < 4; ni++) {
                bf16x8 bf = ld_frag(Wos + (ni * 16 + lm) * 72 + kk + quad * 8);
                oacc[ni] = mfma16(af, bf, oacc[ni]);
            }
        }
    }

    // ---- write out (fp32) + bo, rows < 49 only ----
#pragma unroll
    for (int ni = 0; ni < 4; ni++) {
        int n = ni * 16 + lm;
        float bb = bo[n];
#pragma unroll
        for (int r = 0; r < 4; r++) {
            int m = 16 * wave + quad * 4 + r;
            if (m < 49)
                out[(brow + m) * 64 + n] = oacc[ni][r] + bb;
        }
    }
}

extern "C" void kernel_launch(void* const* d_in, const int* in_sizes, int n_in,
                              void* d_out, int out_size, void* d_ws, size_t ws_size,
                              hipStream_t stream) {
    (void)in_sizes; (void)n_in; (void)out_size; (void)ws_size;
    const float* Xq = (const float*)d_in[0];
    const float* Xk = (const float*)d_in[1];
    const float* Xv = (const float*)d_in[2];
    const float* Wq = (const float*)d_in[3];
    const float* bq = (const float*)d_in[4];
    const float* Wk = (const float*)d_in[5];
    const float* bk = (const float*)d_in[6];
    const float* Wv = (const float*)d_in[7];
    const float* bv = (const float*)d_in[8];
    const float* Wo = (const float*)d_in[9];
    const float* bo = (const float*)d_in[10];

    unsigned short* qkv = (unsigned short*)d_ws;  // needs 3*100352*512*2 = 308 MB

    dim3 gA(4, 784, 3);   // (ntile, mtile, sel): consecutive blocks share A-stripe
    proj_gemm<<<gA, dim3(256), 0, stream>>>(Xq, Xk, Xv, Wq, Wk, Wv, bq, bk, bv, qkv);
    attn_fused<<<dim3(2048), dim3(256), 0, stream>>>(qkv, Wo, bo, (float*)d_out);
}

// Round 2
// 1040.904 us; speedup vs baseline: 1.2140x; 1.2140x over previous
//
#include <hip/hip_runtime.h>

// B=2048, N=49 (7x7), D=512, H=8, DK=DV=64.
// Pipeline: cvt (fp32->bf16 X,W) -> proj_bf16 (m97-style glds GEMM) -> attn.
// Fallback (small ws): R1 proj_f32 (in-flight convert) -> attn.

#define MTOT 100352            // 2048*49
#define XN   51380224          // MTOT*512 elements per X tensor
#define WN   262144            // 512*512

typedef float f32x4 __attribute__((ext_vector_type(4)));
typedef __bf16 bf16x8 __attribute__((ext_vector_type(8)));
typedef unsigned short us8v __attribute__((ext_vector_type(8)));

__device__ __forceinline__ unsigned short f2bf(float f) {
    unsigned int u = __float_as_uint(f);
    u += 0x7fffu + ((u >> 16) & 1u);   // RNE
    return (unsigned short)(u >> 16);
}
__device__ __forceinline__ bf16x8 ld_frag(const unsigned short* p) {
    us8v r = *(const us8v*)p;
    return __builtin_bit_cast(bf16x8, r);
}
__device__ __forceinline__ f32x4 mfma16(bf16x8 a, bf16x8 b, f32x4 c) {
    return __builtin_amdgcn_mfma_f32_16x16x32_bf16(a, b, c, 0, 0, 0);
}
__device__ __forceinline__ void glds16(const unsigned short* g, unsigned short* l) {
    __builtin_amdgcn_global_load_lds(
        (const __attribute__((address_space(1))) unsigned int*)g,
        (__attribute__((address_space(3))) unsigned int*)l, 16, 0, 0);
}

// ---------------- cvt kernels: fp32 -> bf16 (memory-bound) ---------------
__global__ __launch_bounds__(256) void cvt_x(
    const float* __restrict__ x0, const float* __restrict__ x1, const float* __restrict__ x2,
    unsigned short* __restrict__ dst)
{
    const float* src = (blockIdx.z == 0) ? x0 : (blockIdx.z == 1) ? x1 : x2;
    unsigned short* d = dst + (size_t)blockIdx.z * XN;
    const int n4 = XN / 4;
    for (int i = blockIdx.x * 256 + threadIdx.x; i < n4; i += gridDim.x * 256) {
        float4 v = ((const float4*)src)[i];
        ushort4 o; o.x = f2bf(v.x); o.y = f2bf(v.y); o.z = f2bf(v.z); o.w = f2bf(v.w);
        ((ushort4*)d)[i] = o;
    }
}

__global__ __launch_bounds__(256) void cvt_w(
    const float* __restrict__ w0, const float* __restrict__ w1, const float* __restrict__ w2,
    unsigned short* __restrict__ dst)
{
    const float* src = (blockIdx.z == 0) ? w0 : (blockIdx.z == 1) ? w1 : w2;
    unsigned short* d = dst + (size_t)blockIdx.z * WN;
    const int n4 = WN / 4;
    for (int i = blockIdx.x * 256 + threadIdx.x; i < n4; i += gridDim.x * 256) {
        float4 v = ((const float4*)src)[i];
        ushort4 o; o.x = f2bf(v.x); o.y = f2bf(v.y); o.z = f2bf(v.z); o.w = f2bf(v.w);
        ((ushort4*)d)[i] = o;
    }
}

// ---------------- proj_bf16: m97-style GEMM with global_load_lds ---------
// grid (4 ntiles, 784 mtiles, 3 sel). 128x128 tile, BK=64, unpadded LDS
// (glds requires lane-contiguous layout) with XOR column-block swizzle:
// LDS(row, cb) holds global col-block cb ^ (row&7) -> frag ds_read_b128
// banks are conflict-free (lanes lm span all 32 banks in pairs).
__global__ __launch_bounds__(256) void proj_bf16(
    const unsigned short* __restrict__ XB, const unsigned short* __restrict__ WB,
    const float* __restrict__ bq, const float* __restrict__ bk, const float* __restrict__ bv,
    unsigned short* __restrict__ qkv)
{
    const int s = blockIdx.z;
    const unsigned short* X = XB + (size_t)s * XN;
    const unsigned short* W = WB + (size_t)s * WN;
    const float* bias = (s == 0) ? bq : (s == 1) ? bk : bv;
    unsigned short* out = qkv + (size_t)s * XN;

    const int mbase = blockIdx.y * 128;
    const int nbase = blockIdx.x * 128;

    __shared__ __align__(16) unsigned short smA[128 * 64];
    __shared__ __align__(16) unsigned short smB[128 * 64];

    const int tid = threadIdx.x;
    const int wave = tid >> 6, lane = tid & 63;
    const int lm = lane & 15, quad = lane >> 4;
    const int wm = (wave & 1) * 64, wn = (wave >> 1) * 64;

    // staging: pass p covers rows p*32 + wave*8 + lane/8; lane stages the
    // swizzled col-block (lane&7)^(lane/8), 16 B each.
    const int l8 = lane >> 3;
    const int cb = (lane & 7) ^ l8;
    const unsigned short* gA = X + (size_t)(mbase + wave * 8 + l8) * 512 + cb * 8;
    const unsigned short* gB = W + (size_t)(nbase + wave * 8 + l8) * 512 + cb * 8;
    unsigned short* lA = smA + wave * 512;   // wave chunk = 1024 B
    unsigned short* lB = smB + wave * 512;

    f32x4 acc[4][4];
#pragma unroll
    for (int i = 0; i < 4; i++)
#pragma unroll
        for (int jj = 0; jj < 4; jj++) acc[i][jj] = (f32x4){0.f, 0.f, 0.f, 0.f};

    for (int k0 = 0; k0 < 512; k0 += 64) {
#pragma unroll
        for (int p = 0; p < 4; p++) {
            glds16(gA + p * 32 * 512 + k0, lA + p * 2048);
            glds16(gB + p * 32 * 512 + k0, lB + p * 2048);
        }
        __syncthreads();
#pragma unroll
        for (int kk8 = 0; kk8 <= 4; kk8 += 4) {     // kk = 0, 32
            const int pb = ((kk8 + quad) ^ (lm & 7)) * 8;
            bf16x8 af[4], bfr[4];
#pragma unroll
            for (int mi = 0; mi < 4; mi++)
                af[mi] = ld_frag(smA + (wm + mi * 16 + lm) * 64 + pb);
#pragma unroll
            for (int ni = 0; ni < 4; ni++)
                bfr[ni] = ld_frag(smB + (wn + ni * 16 + lm) * 64 + pb);
#pragma unroll
            for (int mi = 0; mi < 4; mi++)
#pragma unroll
                for (int ni = 0; ni < 4; ni++)
                    acc[mi][ni] = mfma16(af[mi], bfr[ni], acc[mi][ni]);
        }
        __syncthreads();
    }

#pragma unroll
    for (int ni = 0; ni < 4; ni++) {
        int n = nbase + wn + ni * 16 + lm;
        float bb = bias[n];
#pragma unroll
        for (int mi = 0; mi < 4; mi++) {
#pragma unroll
            for (int r = 0; r < 4; r++) {
                int m = mbase + wm + mi * 16 + quad * 4 + r;
                out[(size_t)m * 512 + n] = f2bf(acc[mi][ni][r] + bb);
            }
        }
    }
}

// ---------------- fallback proj (R1, in-flight fp32->bf16 convert) -------
__global__ __launch_bounds__(256) void proj_f32(
    const float* __restrict__ Xq, const float* __restrict__ Xk, const float* __restrict__ Xv,
    const float* __restrict__ Wq, const float* __restrict__ Wk, const float* __restrict__ Wv,
    const float* __restrict__ bq, const float* __restrict__ bk, const float* __restrict__ bv,
    unsigned short* __restrict__ outbase)
{
    const int s = blockIdx.z;
    const float* X    = (s == 0) ? Xq : (s == 1) ? Xk : Xv;
    const float* W    = (s == 0) ? Wq : (s == 1) ? Wk : Wv;
    const float* bias = (s == 0) ? bq : (s == 1) ? bk : bv;
    unsigned short* out = outbase + (size_t)s * MTOT * 512;

    const int mbase = blockIdx.y * 128;
    const int nbase = blockIdx.x * 128;

    __shared__ __align__(16) unsigned short smA[128 * 72];
    __shared__ __align__(16) unsigned short smB[128 * 72];

    const int tid  = threadIdx.x;
    const int wave = tid >> 6, lane = tid & 63;
    const int lm   = lane & 15, quad = lane >> 4;
    const int wm   = (wave & 1) * 64, wn = (wave >> 1) * 64;

    f32x4 acc[4][4];
#pragma unroll
    for (int i = 0; i < 4; i++)
#pragma unroll
        for (int jj = 0; jj < 4; jj++) acc[i][jj] = (f32x4){0.f, 0.f, 0.f, 0.f};

    for (int k0 = 0; k0 < 512; k0 += 64) {
#pragma unroll
        for (int i = 0; i < 8; i++) {
            int f   = tid + 256 * i;
            int row = f >> 4;
            int c4  = (f & 15) * 4;
            float4 av = *(const float4*)(X + (size_t)(mbase + row) * 512 + k0 + c4);
            ushort4 wa;
            wa.x = f2bf(av.x); wa.y = f2bf(av.y); wa.z = f2bf(av.z); wa.w = f2bf(av.w);
            *(ushort4*)(smA + row * 72 + c4) = wa;
            float4 bv4 = *(const float4*)(W + (size_t)(nbase + row) * 512 + k0 + c4);
            ushort4 wb;
            wb.x = f2bf(bv4.x); wb.y = f2bf(bv4.y); wb.z = f2bf(bv4.z); wb.w = f2bf(bv4.w);
            *(ushort4*)(smB + row * 72 + c4) = wb;
        }
        __syncthreads();
#pragma unroll
        for (int kk = 0; kk < 64; kk += 32) {
            bf16x8 af[4], bfr[4];
#pragma unroll
            for (int mi = 0; mi < 4; mi++)
                af[mi] = ld_frag(smA + (wm + mi * 16 + lm) * 72 + kk + quad * 8);
#pragma unroll
            for (int ni = 0; ni < 4; ni++)
                bfr[ni] = ld_frag(smB + (wn + ni * 16 + lm) * 72 + kk + quad * 8);
#pragma unroll
            for (int mi = 0; mi < 4; mi++)
#pragma unroll
                for (int ni = 0; ni < 4; ni++)
                    acc[mi][ni] = mfma16(af[mi], bfr[ni], acc[mi][ni]);
        }
        __syncthreads();
    }

#pragma unroll
    for (int mi = 0; mi < 4; mi++) {
#pragma unroll
        for (int ni = 0; ni < 4; ni++) {
            int n = nbase + wn + ni * 16 + lm;
            float bb = bias[n];
#pragma unroll
            for (int r = 0; r < 4; r++) {
                int m = mbase + wm + mi * 16 + quad * 4 + r;
                out[(size_t)m * 512 + n] = f2bf(acc[mi][ni][r] + bb);
            }
        }
    }
}

// ---------------- attn: fused attention + output projection --------------
// one block per batch, 4 waves cooperate per head. Softmax entirely in
// registers (mask+exp per lane on the MFMA C-layout, quad-wide shfl_xor row
// sum). P and O transpose through wave-private LDS rows -> only 2 barriers
// per head (top + post-staging).
__global__ __launch_bounds__(256) void attn_fused(
    const unsigned short* __restrict__ qkv,
    const float* __restrict__ Wo, const float* __restrict__ bo,
    float* __restrict__ out)
{
    const int b = blockIdx.x;
    const int tid = threadIdx.x;
    const int wave = tid >> 6, lane = tid & 63;
    const int lm = lane & 15, quad = lane >> 4;

    const size_t QK = (size_t)MTOT * 512;
    const unsigned short* qg = qkv;
    const unsigned short* kg = qkv + QK;
    const unsigned short* vg = qkv + 2 * QK;
    const size_t brow = (size_t)b * 49;

    __shared__ __align__(16) unsigned short qb[64 * 72];   // q, then P (A-layout)
    __shared__ __align__(16) unsigned short kb[64 * 72];   // k
    __shared__ __align__(16) unsigned short vT[64 * 72];   // v^T [d][key]
    __shared__ __align__(16) unsigned short Wos[64 * 72];  // Wo slice bf16
    __shared__ __align__(16) unsigned short ob[64 * 72];   // O (A-layout)

    // per-thread query rows (C-layout rows: 16*wave + quad*4 + r) and coords
    int qrow[4], qir[4], qic[4];
#pragma unroll
    for (int r = 0; r < 4; r++) {
        qrow[r] = 16 * wave + quad * 4 + r;
        qir[r] = qrow[r] / 7;
        qic[r] = qrow[r] - 7 * qir[r];
    }
    // per-thread key cols (C-layout cols: ni*16 + lm) and coords
    int jr[4], jc[4], jvalid[4];
#pragma unroll
    for (int ni = 0; ni < 4; ni++) {
        int jj = ni * 16 + lm;
        jvalid[ni] = (jj < 49);
        jr[ni] = jj / 7;
        jc[ni] = jj - 7 * jr[ni];
    }

    f32x4 oacc[4];
#pragma unroll
    for (int i = 0; i < 4; i++) oacc[i] = (f32x4){0.f, 0.f, 0.f, 0.f};

    for (int h = 0; h < 8; h++) {
        __syncthreads();   // all waves done reading previous head's buffers
        const int hoff = h * 64;

        // stage q, k (49 x 64 bf16)
#pragma unroll
        for (int i = 0; i < 4; i++) {
            int f = tid + 256 * i;
            if (f < 784) {
                int row = f >> 4, c = (f & 15) * 4;
                size_t src = (brow + row) * 512 + hoff + c;
                *(ushort4*)(qb + row * 72 + c) = *(const ushort4*)(qg + src);
                *(ushort4*)(kb + row * 72 + c) = *(const ushort4*)(kg + src);
            }
        }
        // stage v transposed (coalesced read, scalar transpose write)
#pragma unroll
        for (int i = 0; i < 4; i++) {
            int f = tid + 256 * i;
            if (f < 784) {
                int row = f >> 4, c = (f & 15) * 4;
                ushort4 vv = *(const ushort4*)(vg + (brow + row) * 512 + hoff + c);
                vT[(c + 0) * 72 + row] = vv.x;
                vT[(c + 1) * 72 + row] = vv.y;
                vT[(c + 2) * 72 + row] = vv.z;
                vT[(c + 3) * 72 + row] = vv.w;
            }
        }
        if (tid < 64) {     // zero key-pad cols (0 * garbage must not be NaN)
#pragma unroll
            for (int c = 49; c < 64; c++) vT[tid * 72 + c] = 0;
        }
        // stage Wo slice fp32->bf16 (L2-hot, 16 KB)
#pragma unroll
        for (int i = 0; i < 4; i++) {
            int f = tid + 256 * i;       // 1024 float4
            int row = f >> 4, c = (f & 15) * 4;
            float4 wv = *(const float4*)(Wo + (size_t)row * 512 + hoff + c);
            ushort4 ww;
            ww.x = f2bf(wv.x); ww.y = f2bf(wv.y); ww.z = f2bf(wv.z); ww.w = f2bf(wv.w);
            *(ushort4*)(Wos + row * 72 + c) = ww;
        }
        __syncthreads();

        // ---- S = q k^T : wave owns rows [16w,16w+16), all 64 cols ----
        f32x4 sacc[4];
#pragma unroll
        for (int i = 0; i < 4; i++) sacc[i] = (f32x4){0.f, 0.f, 0.f, 0.f};
#pragma unroll
        for (int kk = 0; kk < 64; kk += 32) {
            bf16x8 af = ld_frag(qb + (16 * wave + lm) * 72 + kk + quad * 8);
#pragma unroll
            for (int ni = 0; ni < 4; ni++)
                sacc[ni] = mfma16(af, ld_frag(kb + (ni * 16 + lm) * 72 + kk + quad * 8), sacc[ni]);
        }

        // ---- mask + exp in registers; row-sum via quad butterfly ----
        float t[4] = {0.f, 0.f, 0.f, 0.f};
#pragma unroll
        for (int ni = 0; ni < 4; ni++) {
#pragma unroll
            for (int r = 0; r < 4; r++) {
                float e = 0.f;
                if (jvalid[ni] && qrow[r] < 49) {
                    int dr = qir[r] - jr[ni]; dr = dr < 0 ? -dr : dr;
                    int dc = qic[r] - jc[ni]; dc = dc < 0 ? -dc : dc;
                    int ch = dr > dc ? dr : dc;
                    float sv = (ch == 1) ? sacc[ni][r] * 0.125f : 0.f;
                    e = __expf(sv);
                }
                sacc[ni][r] = e;
                t[r] += e;
            }
        }
#pragma unroll
        for (int xm = 1; xm < 16; xm <<= 1) {
#pragma unroll
            for (int r = 0; r < 4; r++) t[r] += __shfl_xor(t[r], xm, 64);
        }
        float inv[4];
#pragma unroll
        for (int r = 0; r < 4; r++) inv[r] = (qrow[r] < 49) ? 1.f / t[r] : 0.f;

        // ---- P -> qb (bf16 A-layout); rows are wave-private, no barrier ----
#pragma unroll
        for (int ni = 0; ni < 4; ni++)
#pragma unroll
            for (int r = 0; r < 4; r++)
                qb[qrow[r] * 72 + ni * 16 + lm] = f2bf(sacc[ni][r] * inv[r]);

        // ---- O = P v ----
        f32x4 pacc[4];
#pragma unroll
        for (int i = 0; i < 4; i++) pacc[i] = (f32x4){0.f, 0.f, 0.f, 0.f};
#pragma unroll
        for (int kk = 0; kk < 64; kk += 32) {
            bf16x8 af = ld_frag(qb + (16 * wave + lm) * 72 + kk + quad * 8);
#pragma unroll
            for (int ni = 0; ni < 4; ni++)
                pacc[ni] = mfma16(af, ld_frag(vT + (ni * 16 + lm) * 72 + kk + quad * 8), pacc[ni]);
        }
        // O -> ob (A-layout), wave-private rows
#pragma unroll
        for (int ni = 0; ni < 4; ni++)
#pragma unroll
            for (int r = 0; r < 4; r++)
                ob[qrow[r] * 72 + ni * 16 + lm] = f2bf(pacc[ni][r]);

        // ---- out += O_h @ Wo_h^T ----
#pragma unroll
        for (int kk = 0; kk < 64; kk += 32) {
            bf16x8 af = ld_frag(ob + (16 * wave + lm) * 72 + kk + quad * 8);
#pragma unroll
            for (int ni = 0; ni < 4; ni++)
                oacc[ni] = mfma16(af, ld_frag(Wos + (ni * 16 + lm) * 72 + kk + quad * 8), oacc[ni]);
        }
    }

#pragma unroll
    for (int ni = 0; ni < 4; ni++) {
        int n = ni * 16 + lm;
        float bb = bo[n];
#pragma unroll
        for (int r = 0; r < 4; r++)
            if (qrow[r] < 49)
                out[(brow + qrow[r]) * 64 + n] = oacc[ni][r] + bb;
    }
}

extern "C" void kernel_launch(void* const* d_in, const int* in_sizes, int n_in,
                              void* d_out, int out_size, void* d_ws, size_t ws_size,
                              hipStream_t stream) {
    (void)in_sizes; (void)n_in; (void)out_size;
    const float* Xq = (const float*)d_in[0];
    const float* Xk = (const float*)d_in[1];
    const float* Xv = (const float*)d_in[2];
    const float* Wq = (const float*)d_in[3];
    const float* bq = (const float*)d_in[4];
    const float* Wk = (const float*)d_in[5];
    const float* bk = (const float*)d_in[6];
    const float* Wv = (const float*)d_in[7];
    const float* bv = (const float*)d_in[8];
    const float* Wo = (const float*)d_in[9];
    const float* bo = (const float*)d_in[10];

    unsigned short* qkv = (unsigned short*)d_ws;   // [q|k|v] bf16, 308 MB
    const size_t NEED = ((size_t)6 * XN + 3 * WN) * 2;   // +XB +WB = 618 MB

    if (ws_size >= NEED) {
        unsigned short* XB = qkv + (size_t)3 * XN;
        unsigned short* WB = XB + (size_t)3 * XN;
        cvt_x<<<dim3(4096, 1, 3), 256, 0, stream>>>(Xq, Xk, Xv, XB);
        cvt_w<<<dim3(64, 1, 3), 256, 0, stream>>>(Wq, Wk, Wv, WB);
        proj_bf16<<<dim3(4, 784, 3), 256, 0, stream>>>(XB, WB, bq, bk, bv, qkv);
    } else {
        proj_f32<<<dim3(4, 784, 3), 256, 0, stream>>>(Xq, Xk, Xv, Wq, Wk, Wv,
                                                      bq, bk, bv, qkv);
    }
    attn_fused<<<dim3(2048), dim3(256), 0, stream>>>(qkv, Wo, bo, (float*)d_out);
}